// Round 9
// baseline (269.387 us; speedup 1.0000x reference)
//
#include <hip/hip_runtime.h>

#define SIZE_U 1000
#define SIZE_V 1000
#define DIM    128
#define M_EXTRA 16

typedef float f32x4 __attribute__((ext_vector_type(4)));

// Output flat layout (f32 elements):
//   outputs : [0, 2e6)            (1e6 x 2)
//   lnc_rep : [2e6, 130e6)        (1e6 x 128)
//   dis_rep : [130e6, 258e6)      (1e6 x 128)
//   M       : [258e6, 258e6+2048) (16 x 128)
#define OUT_LNC_OFF 2000000L
#define OUT_DIS_OFF 130000000L
#define OUT_M_OFF   258000000L

// Persistent-block work-stealing (R9). 2048 blocks (8/CU) pull chunk ids from
// an atomic counter in d_ws (zeroed by hipMemsetAsync each launch):
//   copy chunks  (16000): cid = u(1000) x stream(2: lnc|dis) x quarter(8 x 125 rows)
//                         64 KB of pure streaming each
//   score chunks ( 2000): sid = u(1000) x half(2 x 500 rows)
//   M chunk      (    1): id == 18000
// id%9==8 -> score sid=id/9 ; else copy cid=(id/9)*8+(id%9)  (8:1 temporal mix;
// R5/R7 showed big store streams must stay in dedicated, always-resident work).
// Balance error <= 1 chunk (~2-5us); no dispatch tail (blocks persist).
#define N_TOTAL 18001

__global__ __launch_bounds__(256) void bilinear_v9_kernel(
    const float* __restrict__ feature,
    const float* __restrict__ weight,
    const float* __restrict__ wc,
    float* __restrict__ out,
    int* __restrict__ counter)
{
    const int t  = threadIdx.x;
    const int c  = t & 31;   // float4 column 0..31
    const int rg = t >> 5;   // row group 0..7
    const f32x4* dis4 = (const f32x4*)(feature + (size_t)SIZE_U * DIM);

    __shared__ int   s_id;
    __shared__ float lnc_s[DIM];
    __shared__ float proj_s[2][DIM];
    __shared__ float q_s[2][DIM];

    while (true) {
        if (t == 0) s_id = atomicAdd(counter, 1);
        __syncthreads();
        const int id = s_id;
        if (id >= N_TOTAL) break;            // uniform exit

        if (id == N_TOTAL - 1) {
            // ---- M copy (16 x 128) ----
            const f32x4* src = (const f32x4*)(feature + (size_t)(SIZE_U + SIZE_V) * DIM);
            f32x4* dst = (f32x4*)(out + OUT_M_OFF);
            for (int i = t; i < (M_EXTRA * DIM) / 4; i += 256) dst[i] = src[i];
        } else if (id % 9 == 8) {
            // ---- score chunk: u = sid>>1, rows [(sid&1)*500, +500) ----
            const int sid = id / 9;
            const int u   = sid >> 1;
            const int r0  = (sid & 1) * 500;
            const int r1  = r0 + 500;
            const size_t rowbase = (size_t)u * SIZE_V;

            if (t < DIM) lnc_s[t] = feature[(size_t)u * DIM + t];
            __syncthreads();

            {   // proj[k][e] = sum_d weight[k][d][e] * lnc[d]
                const int k = t >> 7, e = t & 127;
                const float* wk = weight + (size_t)k * DIM * DIM + e;
                float acc = 0.f;
                #pragma unroll 8
                for (int d = 0; d < DIM; ++d)
                    acc = fmaf(wk[(size_t)d * DIM], lnc_s[d], acc);
                proj_s[k][e] = acc;
            }
            __syncthreads();

            {   // fold classifier: q[cc][e] = wc[0][cc]*proj0[e] + wc[2+cc]*proj1[e]
                const int cc = t >> 7, e = t & 127;
                q_s[cc][e] = wc[cc] * proj_s[0][e] + wc[2 + cc] * proj_s[1][e];
            }
            __syncthreads();

            const f32x4 q0 = ((const f32x4*)q_s[0])[c];
            const f32x4 q1 = ((const f32x4*)q_s[1])[c];
            float2* outp = (float2*)out;

            #pragma unroll 4
            for (int r = r0 + rg; r < r1; r += 8) {
                const f32x4 dv = dis4[r * 32 + c];
                float t0 = dv.x * q0.x + dv.y * q0.y + dv.z * q0.z + dv.w * q0.w;
                float t1 = dv.x * q1.x + dv.y * q1.y + dv.z * q1.z + dv.w * q1.w;
                #pragma unroll
                for (int off = 16; off; off >>= 1) {
                    t0 += __shfl_xor(t0, off);
                    t1 += __shfl_xor(t1, off);
                }
                if (c == 0)
                    outp[rowbase + r] = make_float2(t0 > 0.f ? t0 : 0.f,
                                                    t1 > 0.f ? t1 : 0.f);
            }
        } else {
            // ---- copy chunk: 125 rows of one stream of one u ----
            const int cid  = (id / 9) * 8 + (id % 9);
            const int u    = cid >> 4;
            const int rem  = cid & 15;
            const int strm = rem >> 3;       // 0 = lnc_rep, 1 = dis_rep
            const int q    = rem & 7;
            const int r0   = q * 125;
            const int r1   = r0 + 125;
            const size_t rowbase = (size_t)u * SIZE_V;

            if (strm == 0) {
                const f32x4 lnc4 = ((const f32x4*)(feature + (size_t)u * DIM))[c];
                f32x4* lr = (f32x4*)(out + OUT_LNC_OFF) + rowbase * (DIM / 4);
                #pragma unroll 4
                for (int r = r0 + rg; r < r1; r += 8)
                    lr[r * 32 + c] = lnc4;
            } else {
                f32x4* dr = (f32x4*)(out + OUT_DIS_OFF) + rowbase * (DIM / 4);
                #pragma unroll 4
                for (int r = r0 + rg; r < r1; r += 8) {
                    const int idx = r * 32 + c;
                    dr[idx] = dis4[idx];
                }
            }
        }
        __syncthreads();   // protect s_id / shared arrays before next grab
    }
}

extern "C" void kernel_launch(void* const* d_in, const int* in_sizes, int n_in,
                              void* d_out, int out_size, void* d_ws, size_t ws_size,
                              hipStream_t stream) {
    const float* feature = (const float*)d_in[0];
    const float* weight  = (const float*)d_in[1];
    const float* wc      = (const float*)d_in[2];
    float* out = (float*)d_out;
    int* counter = (int*)d_ws;

    hipMemsetAsync(counter, 0, sizeof(int), stream);
    bilinear_v9_kernel<<<2048, 256, 0, stream>>>(feature, weight, wc, out, counter);
}

// Round 10
// 231.318 us; speedup vs baseline: 1.1646x; 1.1646x over previous
//
#include <hip/hip_runtime.h>

#define SIZE_U 1000
#define SIZE_V 1000
#define DIM    128
#define M_EXTRA 16

typedef float f32x4 __attribute__((ext_vector_type(4)));

// Output flat layout (f32 elements):
//   outputs : [0, 2e6)            (1e6 x 2)
//   lnc_rep : [2e6, 130e6)        (1e6 x 128)
//   dis_rep : [130e6, 258e6)      (1e6 x 128)
//   M       : [258e6, 258e6+2048) (16 x 128)
#define OUT_LNC_OFF 2000000L
#define OUT_DIS_OFF 130000000L
#define OUT_M_OFF   258000000L

// R10: static schedule, fine chunks, roles interleaved in groups of 17
// (8 lnc : 5 dis : 4 score — matches the 4000:2500:2000 chunk counts; R5/R9
// showed big store streams need dedicated, always-co-resident blocks).
//   b in [0,8500): g=b/17, k=b%17
//     k in [0,8)   : lnc chunk id=g*8+k   in [0,4000): u=id>>2, rows [(id&3)*250,+250)
//                    pure broadcast store of lnc[u] (zero loads in loop)
//     k in [8,13)  : dis chunk id=g*5+k-8 in [0,2500): rb=id/20 (8-row tile),
//                    ug=id%20 (50 u-panels). Tile loaded ONCE into registers
//                    (1 f32x4/thread, coalesced), then 50 pure stores/thread.
//                    Kills the per-iteration load->store dependency AND cuts
//                    dis re-read traffic 50x for the replication stream.
//     k in [13,17) : score chunk id=g*4+k-13 in [0,2000): u=id>>1,
//                    rows [(id&1)*500,+500), unroll-4 shuffle-reduce
//   b == 8500 : M copy
__global__ __launch_bounds__(256) void bilinear_v10_kernel(
    const float* __restrict__ feature,
    const float* __restrict__ weight,
    const float* __restrict__ wc,
    float* __restrict__ out)
{
    const int b = blockIdx.x;
    const int t = threadIdx.x;

    if (b == 8500) {
        const f32x4* src = (const f32x4*)(feature + (size_t)(SIZE_U + SIZE_V) * DIM);
        f32x4* dst = (f32x4*)(out + OUT_M_OFF);
        for (int i = t; i < (M_EXTRA * DIM) / 4; i += 256) dst[i] = src[i];
        return;
    }

    const int g = b / 17;
    const int k = b % 17;
    const int c  = t & 31;   // float4 column 0..31
    const int rg = t >> 5;   // row group 0..7
    const f32x4* dis4 = (const f32x4*)(feature + (size_t)SIZE_U * DIM);

    if (k < 8) {
        // ---- lnc_rep broadcast: pure stores ----
        const int id = g * 8 + k;
        const int u  = id >> 2;
        const int r0 = (id & 3) * 250;
        const f32x4 lnc4 = ((const f32x4*)(feature + (size_t)u * DIM))[c];
        f32x4* lr = (f32x4*)(out + OUT_LNC_OFF) + (size_t)u * SIZE_V * (DIM / 4);
        #pragma unroll 8
        for (int r = r0 + rg; r < r0 + 250; r += 8)
            lr[r * 32 + c] = lnc4;
        return;
    }

    if (k < 13) {
        // ---- dis_rep broadcast: load 8-row tile once, store to 50 u-panels ----
        const int id = g * 5 + (k - 8);
        const int rb = id / 20;          // 8-row tile index, 0..124
        const int u0 = (id % 20) * 50;   // first of 50 u-panels
        const f32x4 dv = dis4[rb * 256 + t];   // coalesced: 1 f32x4/thread
        f32x4* db = (f32x4*)(out + OUT_DIS_OFF);
        const size_t base = (size_t)rb * 256 + t;
        #pragma unroll 5
        for (int u = u0; u < u0 + 50; ++u)
            db[(size_t)u * (SIZE_V * DIM / 4) + base] = dv;
        return;
    }

    // ---- score chunk ----
    const int id = g * 4 + (k - 13);
    const int u  = id >> 1;
    const int r0 = (id & 1) * 500;
    const int r1 = r0 + 500;
    const size_t rowbase = (size_t)u * SIZE_V;

    __shared__ float lnc_s[DIM];
    __shared__ float proj_s[2][DIM];
    __shared__ float q_s[2][DIM];

    if (t < DIM) lnc_s[t] = feature[(size_t)u * DIM + t];
    __syncthreads();

    {   // proj[k][e] = sum_d weight[k][d][e] * lnc[d]
        const int kk = t >> 7, e = t & 127;
        const float* wk = weight + (size_t)kk * DIM * DIM + e;
        float acc = 0.f;
        #pragma unroll 8
        for (int d = 0; d < DIM; ++d)
            acc = fmaf(wk[(size_t)d * DIM], lnc_s[d], acc);
        proj_s[kk][e] = acc;
    }
    __syncthreads();

    {   // fold classifier: q[cc][e] = wc[0][cc]*proj0[e] + wc[2+cc]*proj1[e]
        const int cc = t >> 7, e = t & 127;
        q_s[cc][e] = wc[cc] * proj_s[0][e] + wc[2 + cc] * proj_s[1][e];
    }
    __syncthreads();

    const f32x4 q0 = ((const f32x4*)q_s[0])[c];
    const f32x4 q1 = ((const f32x4*)q_s[1])[c];
    float2* outp = (float2*)out;

    #pragma unroll 4
    for (int r = r0 + rg; r < r1; r += 8) {
        const f32x4 dv = dis4[r * 32 + c];
        float t0 = dv.x * q0.x + dv.y * q0.y + dv.z * q0.z + dv.w * q0.w;
        float t1 = dv.x * q1.x + dv.y * q1.y + dv.z * q1.z + dv.w * q1.w;
        #pragma unroll
        for (int off = 16; off; off >>= 1) {
            t0 += __shfl_xor(t0, off);
            t1 += __shfl_xor(t1, off);
        }
        if (c == 0)
            outp[rowbase + r] = make_float2(t0 > 0.f ? t0 : 0.f,
                                            t1 > 0.f ? t1 : 0.f);
    }
}

extern "C" void kernel_launch(void* const* d_in, const int* in_sizes, int n_in,
                              void* d_out, int out_size, void* d_ws, size_t ws_size,
                              hipStream_t stream) {
    const float* feature = (const float*)d_in[0];
    const float* weight  = (const float*)d_in[1];
    const float* wc      = (const float*)d_in[2];
    float* out = (float*)d_out;

    bilinear_v10_kernel<<<8501, 256, 0, stream>>>(feature, weight, wc, out);
}